// Round 6
// baseline (222.370 us; speedup 1.0000x reference)
//
#include <hip/hip_runtime.h>
#include <math.h>

#define BB 8
#define CC 32
#define NTOK 241   // 4(q 2x2) + 121 + 64 + 36 + 16
#define NKV 237
#define YW 516
#define NSLOT 16   // p2:1 p11:6 p8:4 p6:3 p4:2

// ---------------------------------------------------------------------------
// Kernel A (v5): register-resident streaming pool. 2 blocks/plane (512
// blocks). Thread owns 4 columns, walks rows stride-4 with per-level window
// accumulators in registers (wave-uniform state). Depth-4 load pipeline, no
// barriers/LDS in the hot loop. Window close -> 4 LDS atomicAdds. Phase 2
// W-pools the LDS intermediate; token ownership identical to validated R5.
// ---------------------------------------------------------------------------
struct WS { int idx, s, e, left, slot; float ax, ay, az, aw; };

template <int P>
__device__ __forceinline__ void ws_init(WS& w, int i0, int n, int sb) {
  w.idx = i0;
  w.s = (i0 * 512) / P;
  w.e = ((i0 + 1) * 512 + P - 1) / P;
  w.left = n;
  w.slot = sb;
  w.ax = w.ay = w.az = w.aw = 0.f;
}

template <int P>
__device__ __forceinline__ void ws_step(WS& w, float4 v, int r,
                                        float* __restrict__ Y, int c4) {
  if (w.left > 0) {                          // wave-uniform
    if (r >= w.s && r < w.e) {
      w.ax += v.x; w.ay += v.y; w.az += v.z; w.aw += v.w;
    }
    if (r < w.e && r + 4 >= w.e) {           // last visited row of window
      float* dst = Y + w.slot * YW + c4;
      atomicAdd(dst + 0, w.ax);
      atomicAdd(dst + 1, w.ay);
      atomicAdd(dst + 2, w.az);
      atomicAdd(dst + 3, w.aw);
      w.slot++; w.left--; w.idx++;
      int sn = (w.idx * 512) / P;
      w.e = ((w.idx + 1) * 512 + P - 1) / P;
      bool ov = (sn <= r);                   // adjacent windows overlap <=1 row
      w.ax = ov ? v.x : 0.f; w.ay = ov ? v.y : 0.f;
      w.az = ov ? v.z : 0.f; w.aw = ov ? v.w : 0.f;
      w.s = sn;
    }
  }
}

__global__ __launch_bounds__(512) void pool_kernel(const float* __restrict__ x,
                                                   float* __restrict__ pooled) {
  __shared__ float Ybuf[NSLOT * YW];         // 33,024 B

  const int plane = blockIdx.x >> 1;         // b*32 + c
  const int q = blockIdx.x & 1;
  const int tid = threadIdx.x;

  for (int i = tid; i < NSLOT * YW; i += 512) Ybuf[i] = 0.f;

  // per-q window ownership (validated in R5)
  const int lo = q ? 256 : 0;
  const int NIT = q ? 64 : 72;               // q0 covers 280 rows (p11 w5)
  int i0_2, n_2, i0_11, n_11, i0_8, n_8, i0_6, n_6, i0_4, n_4;
  if (q == 0) {
    i0_2 = 0; n_2 = 1; i0_11 = 0; n_11 = 6; i0_8 = 0; n_8 = 4;
    i0_6 = 0; n_6 = 3; i0_4 = 0; n_4 = 2;
  } else {
    i0_2 = 1; n_2 = 1; i0_11 = 6; n_11 = 5; i0_8 = 4; n_8 = 4;
    i0_6 = 3; n_6 = 3; i0_4 = 2; n_4 = 2;
  }

  WS W2, W11, W8, W6, W4;
  ws_init<2>(W2, i0_2, n_2, 0);
  ws_init<11>(W11, i0_11, n_11, 1);
  ws_init<8>(W8, i0_8, n_8, 7);
  ws_init<6>(W6, i0_6, n_6, 11);
  ws_init<4>(W4, i0_4, n_4, 14);

  const int r0 = tid >> 7;                   // 0..3
  const int c4 = (tid & 127) * 4;
  const float* xp = x + (size_t)plane * (512 * 512);

  __syncthreads();                           // Ybuf zeroed

#define LOADIT(IT) \
  (*(const float4*)(xp + (size_t)min(lo + r0 + 4 * (IT), 511) * 512 + c4))
#define PROCIT(V, IT)                                                          \
  {                                                                            \
    int r = lo + r0 + 4 * (IT);                                                \
    ws_step<2>(W2, V, r, Ybuf, c4);                                            \
    ws_step<11>(W11, V, r, Ybuf, c4);                                          \
    ws_step<8>(W8, V, r, Ybuf, c4);                                            \
    ws_step<6>(W6, V, r, Ybuf, c4);                                            \
    ws_step<4>(W4, V, r, Ybuf, c4);                                            \
  }

  float4 Av = LOADIT(0), Bv = LOADIT(1), Cv = LOADIT(2), Dv = LOADIT(3);
  for (int it = 0; it < NIT; it += 4) {
    PROCIT(Av, it);     Av = LOADIT(it + 4);
    PROCIT(Bv, it + 1); Bv = LOADIT(it + 5);
    PROCIT(Cv, it + 2); Cv = LOADIT(it + 6);
    PROCIT(Dv, it + 3); Dv = LOADIT(it + 7);
  }
#undef LOADIT
#undef PROCIT
  __syncthreads();

  // Phase 2: W-pool owned Y rows into tokens (each token written once).
  const int Ps[5]  = {2, 11, 8, 6, 4};
  const int KBs[5] = {0, 4, 125, 189, 225};
  const int SBs[5] = {0, 1, 7, 11, 14};
  const int i0s[5] = {i0_2, i0_11, i0_8, i0_6, i0_4};
  const int ns[5]  = {n_2, n_11, n_8, n_6, n_4};
  int cum[6]; cum[0] = 0;
#pragma unroll
  for (int l = 0; l < 5; ++l) cum[l + 1] = cum[l] + ns[l] * Ps[l];

  if (tid < cum[5]) {
    int l = 0;
    while (tid >= cum[l + 1]) ++l;
    int P = Ps[l];
    int rel = tid - cum[l];
    int li = rel / P, j = rel - li * P;
    int i = i0s[l] + li;
    int s = (i * 512) / P, e = ((i + 1) * 512 + P - 1) / P;
    int sw = (j * 512) / P, ew = ((j + 1) * 512 + P - 1) / P;
    const float* row = &Ybuf[(SBs[l] + li) * YW];
    float t0 = 0.f, t1 = 0.f, t2 = 0.f, t3 = 0.f;
    int cc = sw;
    for (; cc + 4 <= ew; cc += 4) {
      t0 += row[cc]; t1 += row[cc + 1]; t2 += row[cc + 2]; t3 += row[cc + 3];
    }
    for (; cc < ew; ++cc) t0 += row[cc];
    float val = ((t0 + t1) + (t2 + t3)) / (float)((e - s) * (ew - sw));
    pooled[(size_t)plane * NTOK + KBs[l] + i * P + j] = val;
  }
}

// ---------------------------------------------------------------------------
// Kernel B: token pipeline (dw-conv residual, LN, q/kv linears, attention,
// proj). One block per batch element.
// ---------------------------------------------------------------------------
__global__ __launch_bounds__(512) void attn_kernel(
    const float* __restrict__ pooled,
    const float* __restrict__ q_w, const float* __restrict__ q_b,
    const float* __restrict__ kv_w, const float* __restrict__ kv_b,
    const float* __restrict__ proj_w, const float* __restrict__ proj_b,
    const float* __restrict__ norm_g, const float* __restrict__ norm_b,
    const float* __restrict__ dconv_w, const float* __restrict__ dconv_b,
    float* __restrict__ o_out) {
  __shared__ float pl[CC * NTOK];
  __shared__ float toks[NKV][33];
  __shared__ float kvls[NKV][65];      // k: 0..31, v: 32..63
  __shared__ float kvw[CC * 64];
  __shared__ float dw[4 * CC * 9];
  __shared__ float dbias[4 * CC];
  __shared__ float qbias[CC], kvb[64], gln[CC], bln[CC];
  __shared__ float qtok[4][CC];
  __shared__ float attno[4][33];

  const int b = blockIdx.x, tid = threadIdx.x;
  const float* plg = pooled + (size_t)b * CC * NTOK;
  for (int i = tid; i < CC * NTOK; i += 512) pl[i] = plg[i];
  for (int i = tid; i < CC * 64; i += 512) kvw[i] = kv_w[i];
  for (int i = tid; i < 4 * CC * 9; i += 512) dw[i] = dconv_w[i];
  if (tid < 4 * CC) dbias[tid] = dconv_b[tid];
  if (tid < CC) { qbias[tid] = q_b[tid]; gln[tid] = norm_g[tid]; bln[tid] = norm_b[tid]; }
  if (tid >= 64 && tid < 128) kvb[tid - 64] = kv_b[tid - 64];
  __syncthreads();

  // depthwise 3x3 conv (SAME, zero pad) + residual -> toks
  for (int item = tid; item < NKV * CC; item += 512) {
    int t = item >> 5, c = item & 31;
    int l, p, kb_, tb;
    if (t < 121)      { l = 0; p = 11; kb_ = 4;   tb = 0; }
    else if (t < 185) { l = 1; p = 8;  kb_ = 125; tb = 121; }
    else if (t < 221) { l = 2; p = 6;  kb_ = 189; tb = 185; }
    else              { l = 3; p = 4;  kb_ = 225; tb = 221; }
    int ti = t - tb;
    int i = ti / p, j = ti - i * p;
    const float* plc = pl + c * NTOK + kb_;
    const float* w9 = dw + (l * CC + c) * 9;
    float acc = dbias[l * CC + c];
#pragma unroll
    for (int dy = -1; dy <= 1; ++dy)
#pragma unroll
      for (int dx = -1; dx <= 1; ++dx) {
        int ii = i + dy, jj = j + dx;
        if (ii >= 0 && ii < p && jj >= 0 && jj < p)
          acc += w9[(dy + 1) * 3 + (dx + 1)] * plc[ii * p + jj];
      }
    toks[t][c] = plc[i * p + j] + acc;
  }
  __syncthreads();

  // LayerNorm over C (threads 0..236) ; q linear (threads 384..511)
  if (tid < NKV) {
    float xv[32]; float m = 0.f;
#pragma unroll
    for (int c = 0; c < 32; ++c) { xv[c] = toks[tid][c]; m += xv[c]; }
    m *= (1.0f / 32.0f);
    float v = 0.f;
#pragma unroll
    for (int c = 0; c < 32; ++c) { float d = xv[c] - m; v += d * d; }
    v *= (1.0f / 32.0f);
    float rs = rsqrtf(v + 1e-5f);
#pragma unroll
    for (int c = 0; c < 32; ++c) toks[tid][c] = (xv[c] - m) * rs * gln[c] + bln[c];
  } else if (tid >= 384) {
    int it = tid - 384;
    int n = it >> 5, u = it & 31;
    float acc = qbias[u];
#pragma unroll
    for (int c = 0; c < 32; ++c) acc += pl[c * NTOK + n] * q_w[c * 32 + u];
    qtok[n][u] = acc * 0.25f;         // fold scale = hd^-0.5
  }
  __syncthreads();

  // kv = toks_ln @ kv_w + kv_b   (237 x 64)
  for (int item = tid; item < NKV * 64; item += 512) {
    int t = item >> 6, u = item & 63;
    float acc = kvb[u];
#pragma unroll
    for (int c = 0; c < 32; ++c) acc += toks[t][c] * kvw[c * 64 + u];
    kvls[t][u] = acc;
  }
  __syncthreads();

  // attention: 8 waves <-> 8 (head, query) pairs
  {
    int wave = tid >> 6, lane = tid & 63;
    int h = wave >> 2, qi = wave & 3;
    float qv[16];
#pragma unroll
    for (int d = 0; d < 16; ++d) qv[d] = qtok[qi][h * 16 + d];
    float sc[4];
#pragma unroll
    for (int m = 0; m < 4; ++m) {
      int t = lane + m * 64;
      float s = -1e30f;
      if (t < NKV) {
        s = 0.f;
#pragma unroll
        for (int d = 0; d < 16; ++d) s += qv[d] * kvls[t][h * 16 + d];
      }
      sc[m] = s;
    }
    float mx = fmaxf(fmaxf(sc[0], sc[1]), fmaxf(sc[2], sc[3]));
#pragma unroll
    for (int d = 1; d < 64; d <<= 1) mx = fmaxf(mx, __shfl_xor(mx, d));
    float pr[4]; float ssum = 0.f;
#pragma unroll
    for (int m = 0; m < 4; ++m) {
      int t = lane + m * 64;
      pr[m] = (t < NKV) ? expf(sc[m] - mx) : 0.0f;
      ssum += pr[m];
    }
#pragma unroll
    for (int d = 1; d < 64; d <<= 1) ssum += __shfl_xor(ssum, d);
    float acc[16];
#pragma unroll
    for (int d = 0; d < 16; ++d) acc[d] = 0.f;
#pragma unroll
    for (int m = 0; m < 4; ++m) {
      int t = lane + m * 64;
      if (t < NKV) {
        float p = pr[m];
#pragma unroll
        for (int d = 0; d < 16; ++d) acc[d] += p * kvls[t][32 + h * 16 + d];
      }
    }
#pragma unroll
    for (int d = 0; d < 16; ++d) {
#pragma unroll
      for (int s = 1; s < 64; s <<= 1) acc[d] += __shfl_xor(acc[d], s);
    }
    if (lane == 0) {
      float inv = 1.0f / ssum;
#pragma unroll
      for (int d = 0; d < 16; ++d) attno[qi][h * 16 + d] = acc[d] * inv;
    }
  }
  __syncthreads();

  // proj: (4 x 32) @ proj_w + proj_b -> o_out[(b*32+u)*4 + n]
  if (tid < 128) {
    int n = tid >> 5, u = tid & 31;
    float acc = proj_b[u];
#pragma unroll
    for (int c = 0; c < 32; ++c) acc += attno[n][c] * proj_w[c * 32 + u];
    o_out[((size_t)b * 32 + u) * 4 + n] = acc;
  }
}

// ---------------------------------------------------------------------------
// Kernel C: bilinear upsample 2x2 -> 512x512 (align_corners=False, clamped).
// ---------------------------------------------------------------------------
__global__ __launch_bounds__(256) void upsample_kernel(const float* __restrict__ o_in,
                                                       float* __restrict__ out) {
  const int plane = blockIdx.x >> 3;
  const int chunk = blockIdx.x & 7;
  const int tid = threadIdx.x;
  const int sub = tid >> 7, col4 = tid & 127;

  const float o00 = o_in[plane * 4 + 0];
  const float o01 = o_in[plane * 4 + 1];
  const float o10 = o_in[plane * 4 + 2];
  const float o11 = o_in[plane * 4 + 3];

  float top[4], bot[4];
#pragma unroll
  for (int k = 0; k < 4; ++k) {
    float c = (float)(4 * col4 + k) + 0.5f;
    float ww = c * (1.0f / 256.0f) - 0.5f;
    ww = fminf(fmaxf(ww, 0.0f), 1.0f);
    top[k] = o00 + ww * (o01 - o00);
    bot[k] = o10 + ww * (o11 - o10);
  }
  float* outp = out + (size_t)plane * (512 * 512);
  const int r0 = chunk * 64;
  for (int i = 0; i < 32; ++i) {
    int r = r0 + 2 * i + sub;
    float wh = ((float)r + 0.5f) * (1.0f / 256.0f) - 0.5f;
    wh = fminf(fmaxf(wh, 0.0f), 1.0f);
    float4 v;
    v.x = top[0] + wh * (bot[0] - top[0]);
    v.y = top[1] + wh * (bot[1] - top[1]);
    v.z = top[2] + wh * (bot[2] - top[2]);
    v.w = top[3] + wh * (bot[3] - top[3]);
    *(float4*)(outp + r * 512 + 4 * col4) = v;
  }
}

extern "C" void kernel_launch(void* const* d_in, const int* in_sizes, int n_in,
                              void* d_out, int out_size, void* d_ws, size_t ws_size,
                              hipStream_t stream) {
  const float* x       = (const float*)d_in[0];
  const float* q_w     = (const float*)d_in[1];
  const float* q_b     = (const float*)d_in[2];
  const float* kv_w    = (const float*)d_in[3];
  const float* kv_b    = (const float*)d_in[4];
  const float* proj_w  = (const float*)d_in[5];
  const float* proj_b  = (const float*)d_in[6];
  const float* norm_g  = (const float*)d_in[7];
  const float* norm_b  = (const float*)d_in[8];
  const float* dconv_w = (const float*)d_in[9];
  const float* dconv_b = (const float*)d_in[10];
  float* out = (float*)d_out;

  float* pooled = (float*)d_ws;                     // 256*241 floats
  float* o_ws   = pooled + (size_t)BB * CC * NTOK;  // 1024 floats

  pool_kernel<<<BB * CC * 2, 512, 0, stream>>>(x, pooled);
  attn_kernel<<<BB, 512, 0, stream>>>(pooled, q_w, q_b, kv_w, kv_b, proj_w,
                                      proj_b, norm_g, norm_b, dconv_w, dconv_b,
                                      o_ws);
  upsample_kernel<<<BB * CC * 8, 256, 0, stream>>>(o_ws, out);
}